// Round 1
// baseline (87.911 us; speedup 1.0000x reference)
//
#include <hip/hip_runtime.h>

// QuantumAttention: B=8, S=2048, E=8, H=2, D=4, NQ=8
//
// History: R1 41us (LDS broadcast/row), R3 36us (8 rows/lane), R5 (M=4,
// 1024 blocks) = 4 waves/SIMD -> 3.2x stall factor vs ~9.5us issue floor.
// R6: M=2 rows/lane, grid 2048 (16 row-tiles x 8 j-windows) -> 8 blocks/CU
// = 8 waves/SIMD (VGPR ~50 under (256,8) cap, LDS ~16KB). Quantum merge
// kernel: 64x256 -> 256x64 blocks so all 256 CUs participate (was 64 CUs,
// latency-bound on scattered ws reads).
//
// NOTE: harness poisons the 256MB workspace with a ~40us fill INSIDE the
// timed region (top rocprof dispatch) -- that is the floor; kernel time is
// what we optimize.
//
// Quantum circuit closed-form: c_w = cos(tok[w]+tok[w%4]);
// z[0]=c1..c7, z[q>=1]=c0..cq. Softmax one-pass (scores bounded, fp32 safe);
// 0.5*log2(e) folded into Wq so inner exp is bare v_exp_f32 (exp2).

#define SS 2048
#define EE 8

// grid 2048: bid = b<<8 | h<<7 | rt<<3 | jw.  256 threads = 4 waves.
// Block: rows rt*128..+127 (2 per lane), j-window jw*256..+255 (64 per wave).
extern "C" __global__ __launch_bounds__(256, 8)
void qa_attn6(const float* __restrict__ x, const float* __restrict__ Wq,
              const float* __restrict__ Wk, const float* __restrict__ Wv,
              float* __restrict__ wsD, float4* __restrict__ wsA) {
    __shared__ float wrow[96];                    // wq'(scaled), wk, wv
    __shared__ __align__(16) float4 kv4[512];     // 256 j x {K4,V4} = 8 KB
    __shared__ float rden[3 * 128];               // waves 1..3 partials
    __shared__ __align__(16) float4 racc[3 * 128];// 6 KB

    const int bid = blockIdx.x;
    const int jw = bid & 7, rt = (bid >> 3) & 15, h = (bid >> 7) & 1, b = bid >> 8;
    const int tid = threadIdx.x, lane = tid & 63, w = tid >> 6;

    if (tid < 96) {
        const int grp = tid >> 5, d = (tid >> 3) & 3, e = tid & 7;
        const float* W = (grp == 0) ? Wq : (grp == 1 ? Wk : Wv);
        float val = W[(h * 4 + d) * EE + e];
        if (grp == 0) val *= 0.72134752044f;   // 0.5 * log2(e)
        wrow[tid] = val;
    }
    __syncthreads();   // wrow ready

    // ---- stage K,V for the 256-j window (one j per thread) ----
    {
        const int j = jw * 256 + tid;
        const float* xp = x + ((size_t)(b * SS + j)) * EE;
        float xv[8];
        *(float4*)&xv[0] = *(const float4*)xp;
        *(float4*)&xv[4] = *(const float4*)(xp + 4);
        float kk[4], vv[4];
        #pragma unroll
        for (int d = 0; d < 4; ++d) {
            float sk = 0.f, sv = 0.f;
            #pragma unroll
            for (int e = 0; e < 8; ++e) {
                sk += xv[e] * wrow[32 + d * 8 + e];
                sv += xv[e] * wrow[64 + d * 8 + e];
            }
            kk[d] = sk; vv[d] = sv;
        }
        kv4[tid * 2]     = make_float4(kk[0], kk[1], kk[2], kk[3]);
        kv4[tid * 2 + 1] = make_float4(vv[0], vv[1], vv[2], vv[3]);
    }

    // ---- q' (log2-scaled) for this lane's 2 rows ----
    float q[2][4];
    const int row0 = rt * 128 + lane;
    #pragma unroll
    for (int m = 0; m < 2; ++m) {
        const float* xp = x + ((size_t)(b * SS + row0 + m * 64)) * EE;
        float xv[8];
        *(float4*)&xv[0] = *(const float4*)xp;
        *(float4*)&xv[4] = *(const float4*)(xp + 4);
        #pragma unroll
        for (int d = 0; d < 4; ++d) {
            float s = 0.f;
            #pragma unroll
            for (int e = 0; e < 8; ++e) s += xv[e] * wrow[d * 8 + e];
            q[m][d] = s;
        }
    }
    __syncthreads();   // kv4 ready

    // ---- 64-j slice for this wave, 2 rows per lane ----
    float den[2] = {};
    float acc[2][4] = {};
    const float4* kvp = &kv4[w * 128];
    #pragma unroll 2
    for (int jl = 0; jl < 64; ++jl) {
        const float4 kk = kvp[jl * 2];      // wave-broadcast
        const float4 vv = kvp[jl * 2 + 1];
        #pragma unroll
        for (int m = 0; m < 2; ++m) {
            const float s = q[m][0] * kk.x + q[m][1] * kk.y
                          + q[m][2] * kk.z + q[m][3] * kk.w;
            const float e = __builtin_amdgcn_exp2f(s);
            den[m] += e;
            acc[m][0] += e * vv.x; acc[m][1] += e * vv.y;
            acc[m][2] += e * vv.z; acc[m][3] += e * vv.w;
        }
    }

    // ---- single-stage reduce: waves 1..3 park, wave 0 merges + writes ----
    if (w > 0) {
        #pragma unroll
        for (int m = 0; m < 2; ++m) {
            rden[(w - 1) * 128 + lane + m * 64] = den[m];
            racc[(w - 1) * 128 + lane + m * 64] =
                make_float4(acc[m][0], acc[m][1], acc[m][2], acc[m][3]);
        }
    }
    __syncthreads();
    if (w == 0) {
        #pragma unroll
        for (int m = 0; m < 2; ++m) {
            const int r = lane + m * 64;
            float d = den[m] + rden[r] + rden[128 + r] + rden[256 + r];
            float4 a1 = racc[r], a2 = racc[128 + r], a3 = racc[256 + r];
            float4 a = make_float4(acc[m][0] + a1.x + a2.x + a3.x,
                                   acc[m][1] + a1.y + a2.y + a3.y,
                                   acc[m][2] + a1.z + a2.z + a3.z,
                                   acc[m][3] + a1.w + a2.w + a3.w);
            const size_t idx = ((size_t)((b * 2 + h) * 8 + jw)) * SS + row0 + m * 64;
            wsD[idx] = d;
            wsA[idx] = a;
        }
    }
}

// Merge 8 window-partials per (token, head), divide, closed-form quantum, Wo.
// 256 blocks x 64 threads: one token per thread, all 256 CUs active.
extern "C" __global__ __launch_bounds__(64)
void qa_quantum6(const float* __restrict__ wsD, const float4* __restrict__ wsA,
                 const float* __restrict__ Wo, float* __restrict__ out) {
    __shared__ float wo[64];
    const int tid = threadIdx.x;
    wo[tid] = Wo[tid];
    __syncthreads();

    const int g = blockIdx.x * 64 + tid;   // token 0..16383
    const int b = g >> 11, s = g & 2047;

    float tok[8];
    #pragma unroll
    for (int h = 0; h < 2; ++h) {
        float den = 0.f, a0 = 0.f, a1 = 0.f, a2 = 0.f, a3 = 0.f;
        #pragma unroll
        for (int sl = 0; sl < 8; ++sl) {
            const size_t idx = ((size_t)((b * 2 + h) * 8 + sl)) * SS + s;
            den += wsD[idx];
            const float4 p = wsA[idx];
            a0 += p.x; a1 += p.y; a2 += p.z; a3 += p.w;
        }
        const float inv = 1.f / den;
        tok[h * 4 + 0] = a0 * inv; tok[h * 4 + 1] = a1 * inv;
        tok[h * 4 + 2] = a2 * inv; tok[h * 4 + 3] = a3 * inv;
    }

    float c[8];
    #pragma unroll
    for (int ww = 0; ww < 8; ++ww) c[ww] = __cosf(tok[ww] + tok[ww & 3]);

    float z[8];
    float p = 1.f;
    #pragma unroll
    for (int qq = 1; qq < 8; ++qq) { p *= c[qq]; z[qq] = p; }
    z[0] = p;                       // c1..c7
    #pragma unroll
    for (int qq = 1; qq < 8; ++qq) z[qq] *= c[0];   // c0..cq

    float y[8];
    #pragma unroll
    for (int f = 0; f < 8; ++f) {
        float sum = 0.f;
        #pragma unroll
        for (int qq = 0; qq < 8; ++qq) sum += z[qq] * wo[f * 8 + qq];
        y[f] = sum;
    }
    float* op = out + (size_t)g * 8;
    *(float4*)op       = make_float4(y[0], y[1], y[2], y[3]);
    *(float4*)(op + 4) = make_float4(y[4], y[5], y[6], y[7]);
}

extern "C" void kernel_launch(void* const* d_in, const int* in_sizes, int n_in,
                              void* d_out, int out_size, void* d_ws, size_t ws_size,
                              hipStream_t stream) {
    const float* x  = (const float*)d_in[0];
    const float* Wq = (const float*)d_in[1];
    const float* Wk = (const float*)d_in[2];
    const float* Wv = (const float*)d_in[3];
    const float* Wo = (const float*)d_in[4];
    float* out = (float*)d_out;

    float*  wsD = (float*)d_ws;                          // 16*8*2048 floats = 1 MB
    float4* wsA = (float4*)((char*)d_ws + (16 * 8 * 2048) * sizeof(float)); // 4 MB

    qa_attn6<<<dim3(2048), dim3(256), 0, stream>>>(x, Wq, Wk, Wv, wsD, wsA);
    qa_quantum6<<<dim3(256), dim3(64), 0, stream>>>(wsD, wsA, Wo, out);
}